// Round 1
// baseline (5283.765 us; speedup 1.0000x reference)
//
#include <hip/hip_runtime.h>
#include <hip/hip_bf16.h>

// B=2, L=2048, D=1024, H=16, DH=64, M=2048 (rel rows used: rel[1:2049])
// logits[l,m] = (q[l].k[m] + (m<=l ? q[l].e[2047-l+m] : 0)) / 8
// softmax over all m (no causal mask), out = (attn@v) @ Wo + bo

namespace {
constexpr int Bc = 2, Lc = 2048, Dc = 1024, Hc = 16, DHc = 64;
}

// ---------------- fp32 tiled GEMM: C = A @ W + bias ----------------
// A: [4096, 1024] row-major, W: [1024, 1024] row-major, bias: [1024]
// headsLayout: 1 -> C[((b*16+h)*2048+l)*64+dh] ; 0 -> C[row*1024+col]
__global__ __launch_bounds__(256)
void gemm64(const float* __restrict__ A, const float* __restrict__ W,
            const float* __restrict__ bias, float* __restrict__ C,
            int headsLayout)
{
    __shared__ float a_s[64][17];   // pad 17: 4-row stride -> bank stride 4 (free)
    __shared__ float w_s[16][65];   // pad 65: col stride 4 -> 2-way (free)
    const int tid = threadIdx.x;
    const int r0 = blockIdx.y * 64;
    const int c0 = blockIdx.x * 64;
    const int ti = tid >> 4, tj = tid & 15;
    const int i0 = ti * 4, j0 = tj * 4;

    const int ar = tid >> 2;          // A-stage row 0..63
    const int ak = (tid & 3) * 4;     // A-stage k offset
    const int wr = tid >> 4;          // W-stage row 0..15
    const int wc = (tid & 15) * 4;    // W-stage col

    float acc[4][4] = {};

    for (int kt = 0; kt < Dc; kt += 16) {
        const float4 av = *reinterpret_cast<const float4*>(&A[(size_t)(r0 + ar) * Dc + kt + ak]);
        const float4 wv = *reinterpret_cast<const float4*>(&W[(size_t)(kt + wr) * Dc + c0 + wc]);
        a_s[ar][ak + 0] = av.x; a_s[ar][ak + 1] = av.y;
        a_s[ar][ak + 2] = av.z; a_s[ar][ak + 3] = av.w;
        w_s[wr][wc + 0] = wv.x; w_s[wr][wc + 1] = wv.y;
        w_s[wr][wc + 2] = wv.z; w_s[wr][wc + 3] = wv.w;
        __syncthreads();
        #pragma unroll
        for (int kk = 0; kk < 16; ++kk) {
            float a[4], w[4];
            #pragma unroll
            for (int r = 0; r < 4; ++r) a[r] = a_s[i0 + r][kk];
            #pragma unroll
            for (int c = 0; c < 4; ++c) w[c] = w_s[kk][j0 + c];
            #pragma unroll
            for (int r = 0; r < 4; ++r)
                #pragma unroll
                for (int c = 0; c < 4; ++c)
                    acc[r][c] = fmaf(a[r], w[c], acc[r][c]);
        }
        __syncthreads();
    }

    #pragma unroll
    for (int r = 0; r < 4; ++r) {
        const int row = r0 + i0 + r;
        #pragma unroll
        for (int c = 0; c < 4; ++c) {
            const int col = c0 + j0 + c;
            const float val = acc[r][c] + bias[col];
            if (headsLayout) {
                const int b = row >> 11, l = row & 2047, h = col >> 6, dh = col & 63;
                C[((size_t)(b * Hc + h) * Lc + l) * DHc + dh] = val;
            } else {
                C[(size_t)row * Dc + col] = val;
            }
        }
    }
}

// ---------------- flash attention (fp32), rel bias fused ----------------
// q,k,v: [B*H][L][64]; rel: [2049][64]; ao: [B*L][1024]
// Block: 256 thr, 64 queries; S cols strided (j = tj+16c) for conflict-free
// k-row gather; O cols contiguous (d = 4tj+c). q_s/k_s/v_s XOR-swizzled at
// 16B granularity (blk ^= row&7) -> all b128 reads <=2-way.
__global__ __launch_bounds__(256)
void attn_fp32(const float* __restrict__ q, const float* __restrict__ k,
               const float* __restrict__ v, const float* __restrict__ rel,
               float* __restrict__ ao)
{
    __shared__ float q_s[64 * 64];
    __shared__ float k_s[64 * 64];
    __shared__ float v_s[64 * 64];
    __shared__ float p_s[64 * 65];

    const int tid = threadIdx.x;
    const int qt = blockIdx.x;
    const int bh = blockIdx.y;
    const int b = bh >> 4, h = bh & 15;
    const int l0 = qt * 64;
    const size_t base = (size_t)bh * (Lc * DHc);
    const float* qp = q + base;
    const float* kp = k + base;
    const float* vp = v + base;

    const int ti = tid >> 4, tj = tid & 15;
    const int i0 = ti * 4;

    // stage q tile (swizzled)
    #pragma unroll
    for (int it = 0; it < 4; ++it) {
        const int idx = it * 256 + tid;
        const int row = idx >> 4;
        const int blk = idx & 15;
        const float4 t4 = *reinterpret_cast<const float4*>(
            &qp[(size_t)(l0 + row) * DHc + blk * 4]);
        *reinterpret_cast<float4*>(&q_s[row * 64 + ((blk ^ (row & 7)) << 2)]) = t4;
    }

    float o[4][4] = {};
    float mrow[4] = {-3e30f, -3e30f, -3e30f, -3e30f};
    float lrow[4] = {0.f, 0.f, 0.f, 0.f};

    for (int t = 0; t < 32; ++t) {
        const int m0 = t * 64;
        __syncthreads();   // prior PV reads done before k_s/v_s overwrite
        #pragma unroll
        for (int it = 0; it < 4; ++it) {
            const int idx = it * 256 + tid;
            const int row = idx >> 4;
            const int blk = idx & 15;
            const int soff = row * 64 + ((blk ^ (row & 7)) << 2);
            *reinterpret_cast<float4*>(&k_s[soff]) =
                *reinterpret_cast<const float4*>(&kp[(size_t)(m0 + row) * DHc + blk * 4]);
            *reinterpret_cast<float4*>(&v_s[soff]) =
                *reinterpret_cast<const float4*>(&vp[(size_t)(m0 + row) * DHc + blk * 4]);
        }
        __syncthreads();

        // S = q @ k^T  (rows i0..i0+3, cols tj+16c)
        float s[4][4] = {};
        #pragma unroll
        for (int dd = 0; dd < 16; ++dd) {
            float4 qv[4], kv[4];
            #pragma unroll
            for (int r = 0; r < 4; ++r) {
                const int row = i0 + r;
                qv[r] = *reinterpret_cast<const float4*>(
                    &q_s[row * 64 + ((dd ^ (row & 7)) << 2)]);
            }
            #pragma unroll
            for (int c = 0; c < 4; ++c) {
                const int row = tj + 16 * c;
                kv[c] = *reinterpret_cast<const float4*>(
                    &k_s[row * 64 + ((dd ^ (row & 7)) << 2)]);
            }
            #pragma unroll
            for (int r = 0; r < 4; ++r)
                #pragma unroll
                for (int c = 0; c < 4; ++c)
                    s[r][c] += qv[r].x * kv[c].x + qv[r].y * kv[c].y
                             + qv[r].z * kv[c].z + qv[r].w * kv[c].w;
        }

        // rel bias: + q[l] . e[2047-l+m] for m<=l  (e = rel[1:], so row 2048-l+m)
        if (m0 <= l0 + 63) {
            #pragma unroll
            for (int r = 0; r < 4; ++r) {
                const int row = i0 + r;
                const int l = l0 + row;
                float4 qr[16];
                #pragma unroll
                for (int blkq = 0; blkq < 16; ++blkq)
                    qr[blkq] = *reinterpret_cast<const float4*>(
                        &q_s[row * 64 + ((blkq ^ (row & 7)) << 2)]);
                #pragma unroll
                for (int c = 0; c < 4; ++c) {
                    const int m = m0 + tj + 16 * c;
                    if (m <= l) {
                        const float* ep = rel + (size_t)(2048 - l + m) * DHc;
                        float racc = 0.f;
                        #pragma unroll
                        for (int blkq = 0; blkq < 16; ++blkq) {
                            const float4 ev = *reinterpret_cast<const float4*>(&ep[blkq * 4]);
                            racc += qr[blkq].x * ev.x + qr[blkq].y * ev.y
                                  + qr[blkq].z * ev.z + qr[blkq].w * ev.w;
                        }
                        s[r][c] += racc;
                    }
                }
            }
        }

        #pragma unroll
        for (int r = 0; r < 4; ++r)
            #pragma unroll
            for (int c = 0; c < 4; ++c)
                s[r][c] *= 0.125f;

        // online softmax (16 tj-lanes share each row; lane bits 0..3 = tj)
        float pm[4];
        #pragma unroll
        for (int r = 0; r < 4; ++r)
            pm[r] = fmaxf(fmaxf(s[r][0], s[r][1]), fmaxf(s[r][2], s[r][3]));
        #pragma unroll
        for (int off = 1; off < 16; off <<= 1)
            #pragma unroll
            for (int r = 0; r < 4; ++r)
                pm[r] = fmaxf(pm[r], __shfl_xor(pm[r], off));

        float alpha[4];
        #pragma unroll
        for (int r = 0; r < 4; ++r) {
            const float mn = fmaxf(mrow[r], pm[r]);
            alpha[r] = __expf(mrow[r] - mn);
            mrow[r] = mn;
        }
        float rs[4] = {0.f, 0.f, 0.f, 0.f};
        #pragma unroll
        for (int r = 0; r < 4; ++r)
            #pragma unroll
            for (int c = 0; c < 4; ++c) {
                const float p = __expf(s[r][c] - mrow[r]);
                s[r][c] = p;
                rs[r] += p;
            }
        #pragma unroll
        for (int off = 1; off < 16; off <<= 1)
            #pragma unroll
            for (int r = 0; r < 4; ++r)
                rs[r] += __shfl_xor(rs[r], off);
        #pragma unroll
        for (int r = 0; r < 4; ++r) {
            lrow[r] = lrow[r] * alpha[r] + rs[r];
            #pragma unroll
            for (int c = 0; c < 4; ++c)
                o[r][c] *= alpha[r];
        }

        // store P (pad-65: store 2-way, read broadcast)
        #pragma unroll
        for (int r = 0; r < 4; ++r)
            #pragma unroll
            for (int c = 0; c < 4; ++c)
                p_s[(i0 + r) * 65 + tj + 16 * c] = s[r][c];
        __syncthreads();

        // O += P @ V   (O cols d = 4*tj + c)
        #pragma unroll 4
        for (int j4 = 0; j4 < 64; j4 += 4) {
            float4 vv[4];
            #pragma unroll
            for (int jj = 0; jj < 4; ++jj) {
                const int j = j4 + jj;
                vv[jj] = *reinterpret_cast<const float4*>(
                    &v_s[j * 64 + ((tj ^ (j & 7)) << 2)]);
            }
            #pragma unroll
            for (int r = 0; r < 4; ++r) {
                #pragma unroll
                for (int jj = 0; jj < 4; ++jj) {
                    const float p = p_s[(i0 + r) * 65 + j4 + jj];
                    o[r][0] = fmaf(p, vv[jj].x, o[r][0]);
                    o[r][1] = fmaf(p, vv[jj].y, o[r][1]);
                    o[r][2] = fmaf(p, vv[jj].z, o[r][2]);
                    o[r][3] = fmaf(p, vv[jj].w, o[r][3]);
                }
            }
        }
    }

    // normalize + write ao[B*L][1024] (row-major for final GEMM)
    #pragma unroll
    for (int r = 0; r < 4; ++r) {
        const float inv = 1.0f / lrow[r];
        const int row = b * Lc + l0 + i0 + r;
        float4 ov;
        ov.x = o[r][0] * inv; ov.y = o[r][1] * inv;
        ov.z = o[r][2] * inv; ov.w = o[r][3] * inv;
        *reinterpret_cast<float4*>(&ao[(size_t)row * Dc + h * DHc + tj * 4]) = ov;
    }
}

extern "C" void kernel_launch(void* const* d_in, const int* in_sizes, int n_in,
                              void* d_out, int out_size, void* d_ws, size_t ws_size,
                              hipStream_t stream) {
    (void)in_sizes; (void)n_in; (void)out_size; (void)ws_size;
    const float* query = (const float*)d_in[0];
    const float* key   = (const float*)d_in[1];
    const float* value = (const float*)d_in[2];
    const float* Wq    = (const float*)d_in[3];
    const float* bq    = (const float*)d_in[4];
    const float* Wk    = (const float*)d_in[5];
    const float* bk    = (const float*)d_in[6];
    const float* Wv    = (const float*)d_in[7];
    const float* bv    = (const float*)d_in[8];
    const float* Wo    = (const float*)d_in[9];
    const float* bo    = (const float*)d_in[10];
    const float* rel   = (const float*)d_in[11];
    float* out = (float*)d_out;

    float* q_ws = (float*)d_ws;                 // [B,H,L,64] 16 MiB
    float* k_ws = q_ws + 4194304;               // 16 MiB
    float* v_ws = k_ws + 4194304;               // 16 MiB
    float* ao   = v_ws + 4194304;               // [B*L, 1024] 16 MiB

    const dim3 blk(256);
    const dim3 gproj(16, 64);                   // cols x rows of 64x64 tiles
    gemm64<<<gproj, blk, 0, stream>>>(query, Wq, bq, q_ws, 1);
    gemm64<<<gproj, blk, 0, stream>>>(key,   Wk, bk, k_ws, 1);
    gemm64<<<gproj, blk, 0, stream>>>(value, Wv, bv, v_ws, 1);

    attn_fp32<<<dim3(32, 32), blk, 0, stream>>>(q_ws, k_ws, v_ws, rel, ao);

    gemm64<<<gproj, blk, 0, stream>>>(ao, Wo, bo, out, 0);
}

// Round 2
// 307.013 us; speedup vs baseline: 17.2103x; 17.2103x over previous
//
#include <hip/hip_runtime.h>
#include <hip/hip_bf16.h>

// B=2, L=2048, D=1024, H=16, DH=64, M=2048
// logits[l,m] = (q[l].k[m] + (m<=l ? q[l].E[2047+m-l] : 0)) / 8, E[j]=rel[j+1]
// softmax over all m, out = (attn@v reshaped) @ Wo + bo
// Full bf16-MFMA pipeline; rel handled by incremental banded GEMM + shifted gather.

typedef __bf16 v8bf __attribute__((ext_vector_type(8)));
typedef __bf16 v4bf __attribute__((ext_vector_type(4)));
typedef float f32x4 __attribute__((ext_vector_type(4)));

#define MFMA16(A, B, C) __builtin_amdgcn_mfma_f32_16x16x32_bf16((A), (B), (C), 0, 0, 0)

// ---------------- fp32 -> bf16 cast (4 elems/thread) ----------------
__global__ __launch_bounds__(256)
void cast_f32_bf16(const float* __restrict__ in, __bf16* __restrict__ out, int n4)
{
    const int i = blockIdx.x * 256 + threadIdx.x;
    if (i >= n4) return;
    const float4 v = reinterpret_cast<const float4*>(in)[i];
    v4bf o;
    o[0] = (__bf16)v.x; o[1] = (__bf16)v.y; o[2] = (__bf16)v.z; o[3] = (__bf16)v.w;
    reinterpret_cast<v4bf*>(out)[i] = o;
}

// ---------------- rel[1:2049] -> E_bf [2112][64] bf16, zero-padded ----------------
__global__ __launch_bounds__(256)
void cast_rel(const float* __restrict__ rel, __bf16* __restrict__ E)
{
    const int i = blockIdx.x * 256 + threadIdx.x;   // unit = 4 elems; 2112*16 units
    if (i >= 2112 * 16) return;
    const int base = i * 4;
    const int row = base >> 6;
    v4bf o;
    if (row < 2048) {
        const float4 v = *reinterpret_cast<const float4*>(&rel[(size_t)(row + 1) * 64 + (base & 63)]);
        o[0] = (__bf16)v.x; o[1] = (__bf16)v.y; o[2] = (__bf16)v.z; o[3] = (__bf16)v.w;
    } else {
        o[0] = (__bf16)0.f; o[1] = (__bf16)0.f; o[2] = (__bf16)0.f; o[3] = (__bf16)0.f;
    }
    *reinterpret_cast<v4bf*>(&E[base]) = o;
}

// ---------------- W [1024][1024] fp32 -> Wt [n][k] bf16 (transpose+cast) ----------------
__global__ __launch_bounds__(256)
void transpose_cast_w(const float* __restrict__ W, __bf16* __restrict__ Wt)
{
    __shared__ float tile[64][65];
    const int r0 = blockIdx.y * 64, c0 = blockIdx.x * 64;
    const int tr = threadIdx.x >> 4;
    const int tc = (threadIdx.x & 15) * 4;
    #pragma unroll
    for (int p = 0; p < 4; ++p) {
        const int r = tr + p * 16;
        const float4 v = *reinterpret_cast<const float4*>(&W[(size_t)(r0 + r) * 1024 + c0 + tc]);
        tile[r][tc + 0] = v.x; tile[r][tc + 1] = v.y; tile[r][tc + 2] = v.z; tile[r][tc + 3] = v.w;
    }
    __syncthreads();
    #pragma unroll
    for (int p = 0; p < 4; ++p) {
        const int cr = tr + p * 16;          // output row = original column
        v4bf o;
        o[0] = (__bf16)tile[tc + 0][cr];
        o[1] = (__bf16)tile[tc + 1][cr];
        o[2] = (__bf16)tile[tc + 2][cr];
        o[3] = (__bf16)tile[tc + 3][cr];
        *reinterpret_cast<v4bf*>(&Wt[(size_t)(c0 + cr) * 1024 + r0 + tc]) = o;
    }
}

// ---------------- bf16 MFMA GEMM: C = A[4096x1024] @ Wt^T + bias ----------------
// Wt is [n][k] (pre-transposed). mode 0: fp32 flat out; mode 1: bf16 heads layout.
__global__ __launch_bounds__(256)
void gemm_bf16(const __bf16* __restrict__ A, const __bf16* __restrict__ Wt,
               const float* __restrict__ bias, float* __restrict__ Cf,
               __bf16* __restrict__ Cb, int mode)
{
    __shared__ __bf16 As[2][128 * 64];
    __shared__ __bf16 Ws[2][64 * 64];
    const int tid = threadIdx.x;
    const int wid = tid >> 6, lane = tid & 63, g = lane >> 4, li = lane & 15;
    const int r0 = blockIdx.y * 128, c0 = blockIdx.x * 64;
    const int wr = wid >> 1, wc = wid & 1;
    const int sr = tid >> 3, sb = tid & 7;

    f32x4 acc[4][2];
    #pragma unroll
    for (int a = 0; a < 4; ++a)
        #pragma unroll
        for (int b2 = 0; b2 < 2; ++b2) acc[a][b2] = f32x4{0.f, 0.f, 0.f, 0.f};

    v8bf areg[4], wreg[2];

    // prologue stage kt=0
    #pragma unroll
    for (int p = 0; p < 4; ++p)
        areg[p] = *reinterpret_cast<const v8bf*>(&A[(size_t)(r0 + sr + 32 * p) * 1024 + sb * 8]);
    #pragma unroll
    for (int p = 0; p < 2; ++p)
        wreg[p] = *reinterpret_cast<const v8bf*>(&Wt[(size_t)(c0 + sr + 32 * p) * 1024 + sb * 8]);
    #pragma unroll
    for (int p = 0; p < 4; ++p) {
        const int row = sr + 32 * p;
        *reinterpret_cast<v8bf*>(&As[0][row * 64 + ((sb ^ (row & 7)) << 3)]) = areg[p];
    }
    #pragma unroll
    for (int p = 0; p < 2; ++p) {
        const int row = sr + 32 * p;
        *reinterpret_cast<v8bf*>(&Ws[0][row * 64 + ((sb ^ (row & 7)) << 3)]) = wreg[p];
    }
    __syncthreads();

    for (int ki = 0; ki < 16; ++ki) {
        const int cur = ki & 1;
        if (ki < 15) {
            const int kt = (ki + 1) * 64;
            #pragma unroll
            for (int p = 0; p < 4; ++p)
                areg[p] = *reinterpret_cast<const v8bf*>(&A[(size_t)(r0 + sr + 32 * p) * 1024 + kt + sb * 8]);
            #pragma unroll
            for (int p = 0; p < 2; ++p)
                wreg[p] = *reinterpret_cast<const v8bf*>(&Wt[(size_t)(c0 + sr + 32 * p) * 1024 + kt + sb * 8]);
        }
        #pragma unroll
        for (int ks = 0; ks < 2; ++ks) {
            v8bf af[4], bfr[2];
            #pragma unroll
            for (int fm = 0; fm < 4; ++fm) {
                const int row = wr * 64 + fm * 16 + li;
                af[fm] = *reinterpret_cast<const v8bf*>(
                    &As[cur][row * 64 + (((ks * 4 + g) ^ (row & 7)) << 3)]);
            }
            #pragma unroll
            for (int fn = 0; fn < 2; ++fn) {
                const int row = wc * 32 + fn * 16 + li;
                bfr[fn] = *reinterpret_cast<const v8bf*>(
                    &Ws[cur][row * 64 + (((ks * 4 + g) ^ (row & 7)) << 3)]);
            }
            #pragma unroll
            for (int fm = 0; fm < 4; ++fm)
                #pragma unroll
                for (int fn = 0; fn < 2; ++fn)
                    acc[fm][fn] = MFMA16(af[fm], bfr[fn], acc[fm][fn]);
        }
        if (ki < 15) {
            const int nxt = cur ^ 1;
            #pragma unroll
            for (int p = 0; p < 4; ++p) {
                const int row = sr + 32 * p;
                *reinterpret_cast<v8bf*>(&As[nxt][row * 64 + ((sb ^ (row & 7)) << 3)]) = areg[p];
            }
            #pragma unroll
            for (int p = 0; p < 2; ++p) {
                const int row = sr + 32 * p;
                *reinterpret_cast<v8bf*>(&Ws[nxt][row * 64 + ((sb ^ (row & 7)) << 3)]) = wreg[p];
            }
        }
        __syncthreads();
    }

    // epilogue
    #pragma unroll
    for (int fn = 0; fn < 2; ++fn) {
        const int col = c0 + wc * 32 + fn * 16 + li;
        const float bb = bias[col];
        #pragma unroll
        for (int fm = 0; fm < 4; ++fm)
            #pragma unroll
            for (int reg = 0; reg < 4; ++reg) {
                const int row = r0 + wr * 64 + fm * 16 + 4 * g + reg;
                const float val = acc[fm][fn][reg] + bb;
                if (mode == 0) {
                    Cf[(size_t)row * 1024 + col] = val;
                } else {
                    const int b = row >> 11, l = row & 2047, h = col >> 6, dh = col & 63;
                    Cb[((size_t)(b * 16 + h) * 2048 + l) * 64 + dh] = (__bf16)val;
                }
            }
    }
}

// ---------------- fused MFMA flash attention with banded-GEMM rel ----------------
// q,k,v: [32][2048][64] bf16; E: [2112][64] bf16 (E[j]=rel[j+1], zero pad >=2048)
// ao: [4096][1024] bf16.  Block = 256 thr = 4 waves, 64 queries; 32 m-steps of 64.
__global__ __launch_bounds__(256)
void attn_mfma(const __bf16* __restrict__ q, const __bf16* __restrict__ k,
               const __bf16* __restrict__ v, const __bf16* __restrict__ E,
               __bf16* __restrict__ ao)
{
    __shared__ __bf16 Kl[2][64 * 64];     // [m][d], 16B-block XOR swizzle
    __shared__ __bf16 Vt[2][64 * 64];     // transposed: [d][m], swizzled
    __shared__ __bf16 El[2][64 * 64];     // e-window rows, swizzled
    __shared__ __bf16 Tl[64 * 136];       // T gather buf: cols [0,68)=buf0, [68,136)=buf1
    __shared__ __bf16 Pl[4][16 * 64];     // per-wave P strip, swizzled

    const int tid = threadIdx.x;
    const int wid = tid >> 6, lane = tid & 63, g = lane >> 4, li = lane & 15;
    const int qt = blockIdx.x, bh = blockIdx.y;
    const int l0 = qt * 64;
    const size_t hbase = (size_t)bh * (2048 * 64);
    const __bf16* qp = q + hbase;
    const __bf16* kp = k + hbase;
    const __bf16* vp = v + hbase;
    const int w0i = 1984 - 64 * qt;       // first e-block base (>=0)

    const int srow0 = tid >> 3, sblk = tid & 7, srow1 = (tid >> 3) + 32;
    const int vm = tid & 63, vdb = tid >> 6;

    // Q A-fragments, held in registers for whole kernel
    v8bf qf[2];
    {
        const __bf16* qrow = qp + (size_t)(l0 + wid * 16 + li) * 64 + g * 8;
        qf[0] = *reinterpret_cast<const v8bf*>(qrow);
        qf[1] = *reinterpret_cast<const v8bf*>(qrow + 32);
    }

    f32x4 oacc[4];
    #pragma unroll
    for (int i = 0; i < 4; ++i) oacc[i] = f32x4{0.f, 0.f, 0.f, 0.f};
    float mrow[4] = {-3e30f, -3e30f, -3e30f, -3e30f};
    float lrow[4] = {0.f, 0.f, 0.f, 0.f};

    v8bf kreg[2], vreg[2], ereg[2];

    // ---- prologue staging: K[0], V[0], E lo -> El[1], E hi(t=0) -> El[0] ----
    kreg[0] = *reinterpret_cast<const v8bf*>(&kp[(size_t)srow0 * 64 + sblk * 8]);
    kreg[1] = *reinterpret_cast<const v8bf*>(&kp[(size_t)srow1 * 64 + sblk * 8]);
    vreg[0] = *reinterpret_cast<const v8bf*>(&vp[(size_t)vm * 64 + vdb * 16]);
    vreg[1] = *reinterpret_cast<const v8bf*>(&vp[(size_t)vm * 64 + vdb * 16 + 8]);
    ereg[0] = *reinterpret_cast<const v8bf*>(&E[(size_t)(w0i + srow0) * 64 + sblk * 8]);
    ereg[1] = *reinterpret_cast<const v8bf*>(&E[(size_t)(w0i + srow1) * 64 + sblk * 8]);
    v8bf ereg2[2];
    ereg2[0] = *reinterpret_cast<const v8bf*>(&E[(size_t)(w0i + 64 + srow0) * 64 + sblk * 8]);
    ereg2[1] = *reinterpret_cast<const v8bf*>(&E[(size_t)(w0i + 64 + srow1) * 64 + sblk * 8]);

    *reinterpret_cast<v8bf*>(&Kl[0][srow0 * 64 + ((sblk ^ (srow0 & 7)) << 3)]) = kreg[0];
    *reinterpret_cast<v8bf*>(&Kl[0][srow1 * 64 + ((sblk ^ (srow1 & 7)) << 3)]) = kreg[1];
    #pragma unroll
    for (int j = 0; j < 16; ++j) {
        const int d = vdb * 16 + j;
        Vt[0][d * 64 + (((vm >> 3) ^ (d & 7)) << 3) + (vm & 7)] = (j < 8) ? vreg[0][j] : vreg[1][j - 8];
    }
    *reinterpret_cast<v8bf*>(&El[1][srow0 * 64 + ((sblk ^ (srow0 & 7)) << 3)]) = ereg[0];
    *reinterpret_cast<v8bf*>(&El[1][srow1 * 64 + ((sblk ^ (srow1 & 7)) << 3)]) = ereg[1];
    *reinterpret_cast<v8bf*>(&El[0][srow0 * 64 + ((sblk ^ (srow0 & 7)) << 3)]) = ereg2[0];
    *reinterpret_cast<v8bf*>(&El[0][srow1 * 64 + ((sblk ^ (srow1 & 7)) << 3)]) = ereg2[1];
    __syncthreads();

    // ---- prologue T-GEMM: lo block (El[1]) -> Tl cols [0,68) ----
    {
        f32x4 tacc[4];
        #pragma unroll
        for (int i = 0; i < 4; ++i) tacc[i] = f32x4{0.f, 0.f, 0.f, 0.f};
        #pragma unroll
        for (int ks = 0; ks < 2; ++ks)
            #pragma unroll
            for (int rn = 0; rn < 4; ++rn) {
                const int er = rn * 16 + li;
                const v8bf eb = *reinterpret_cast<const v8bf*>(
                    &El[1][er * 64 + (((ks * 4 + g) ^ (er & 7)) << 3)]);
                tacc[rn] = MFMA16(qf[ks], eb, tacc[rn]);
            }
        #pragma unroll
        for (int rn = 0; rn < 4; ++rn)
            #pragma unroll
            for (int reg = 0; reg < 4; ++reg)
                Tl[(wid * 16 + 4 * g + reg) * 136 + rn * 16 + li] = (__bf16)tacc[rn][reg];
    }
    __syncthreads();   // protect El[1] from t=0's prefetch overwrite

    for (int t = 0; t < 32; ++t) {
        const int cur = t & 1, nxt = cur ^ 1;
        const bool relNow = (t <= qt);
        const bool relNext = (t + 1 <= qt);

        // ---- prefetch next tiles into registers (written to LDS after compute) ----
        if (t < 31) {
            const int m1 = (t + 1) * 64;
            kreg[0] = *reinterpret_cast<const v8bf*>(&kp[(size_t)(m1 + srow0) * 64 + sblk * 8]);
            kreg[1] = *reinterpret_cast<const v8bf*>(&kp[(size_t)(m1 + srow1) * 64 + sblk * 8]);
            vreg[0] = *reinterpret_cast<const v8bf*>(&vp[(size_t)(m1 + vm) * 64 + vdb * 16]);
            vreg[1] = *reinterpret_cast<const v8bf*>(&vp[(size_t)(m1 + vm) * 64 + vdb * 16 + 8]);
            if (relNext) {
                const int wb = w0i + 64 * (t + 1) + 64;
                ereg[0] = *reinterpret_cast<const v8bf*>(&E[(size_t)(wb + srow0) * 64 + sblk * 8]);
                ereg[1] = *reinterpret_cast<const v8bf*>(&E[(size_t)(wb + srow1) * 64 + sblk * 8]);
            }
        }

        // ---- S = Q K^T ----
        f32x4 sacc[4];
        #pragma unroll
        for (int i = 0; i < 4; ++i) sacc[i] = f32x4{0.f, 0.f, 0.f, 0.f};
        #pragma unroll
        for (int ks = 0; ks < 2; ++ks)
            #pragma unroll
            for (int fn = 0; fn < 4; ++fn) {
                const int kr = fn * 16 + li;
                const v8bf kb = *reinterpret_cast<const v8bf*>(
                    &Kl[cur][kr * 64 + (((ks * 4 + g) ^ (kr & 7)) << 3)]);
                sacc[fn] = MFMA16(qf[ks], kb, sacc[fn]);
            }

        // ---- T-GEMM: new hi e-block -> Tl cols [nxt*68, nxt*68+64) ----
        if (relNow) {
            f32x4 tacc[4];
            #pragma unroll
            for (int i = 0; i < 4; ++i) tacc[i] = f32x4{0.f, 0.f, 0.f, 0.f};
            #pragma unroll
            for (int ks = 0; ks < 2; ++ks)
                #pragma unroll
                for (int rn = 0; rn < 4; ++rn) {
                    const int er = rn * 16 + li;
                    const v8bf eb = *reinterpret_cast<const v8bf*>(
                        &El[cur][er * 64 + (((ks * 4 + g) ^ (er & 7)) << 3)]);
                    tacc[rn] = MFMA16(qf[ks], eb, tacc[rn]);
                }
            const int tb = nxt * 68;
            #pragma unroll
            for (int rn = 0; rn < 4; ++rn)
                #pragma unroll
                for (int reg = 0; reg < 4; ++reg)
                    Tl[(wid * 16 + 4 * g + reg) * 136 + tb + rn * 16 + li] = (__bf16)tacc[rn][reg];
        }

        // ---- rel gather (wave-private T rows; same-wave LDS ordering suffices) ----
        if (relNow) {
            const int lob = cur * 68, hib = nxt * 68;
            #pragma unroll
            for (int fn = 0; fn < 4; ++fn)
                #pragma unroll
                for (int reg = 0; reg < 4; ++reg) {
                    const int lr = wid * 16 + 4 * g + reg;     // tile-local l row
                    const int mc = fn * 16 + li;               // tile-local m col
                    const int colv = 63 + mc - lr;             // 0..126
                    const int addr = lr * 136 + (colv < 64 ? lob + colv : hib + colv - 64);
                    const float tv = (float)Tl[addr];
                    if ((t < qt) || (mc <= lr)) sacc[fn][reg] += tv;
                }
        }

        #pragma unroll
        for (int fn = 0; fn < 4; ++fn) sacc[fn] *= 0.125f;

        // ---- online softmax (rows live in 16-lane li-groups) ----
        float alpha[4], rsum[4];
        #pragma unroll
        for (int reg = 0; reg < 4; ++reg) {
            float mx = fmaxf(fmaxf(sacc[0][reg], sacc[1][reg]), fmaxf(sacc[2][reg], sacc[3][reg]));
            mx = fmaxf(mx, __shfl_xor(mx, 1));
            mx = fmaxf(mx, __shfl_xor(mx, 2));
            mx = fmaxf(mx, __shfl_xor(mx, 4));
            mx = fmaxf(mx, __shfl_xor(mx, 8));
            const float mn = fmaxf(mrow[reg], mx);
            alpha[reg] = __expf(mrow[reg] - mn);
            mrow[reg] = mn;
            rsum[reg] = 0.f;
        }
        #pragma unroll
        for (int fn = 0; fn < 4; ++fn)
            #pragma unroll
            for (int reg = 0; reg < 4; ++reg) {
                const float p = __expf(sacc[fn][reg] - mrow[reg]);
                rsum[reg] += p;
                const int pr = 4 * g + reg;
                const int mc = fn * 16 + li;
                Pl[wid][pr * 64 + (((mc >> 3) ^ (pr & 7)) << 3) + (mc & 7)] = (__bf16)p;
            }
        #pragma unroll
        for (int reg = 0; reg < 4; ++reg) {
            float rs = rsum[reg];
            rs += __shfl_xor(rs, 1);
            rs += __shfl_xor(rs, 2);
            rs += __shfl_xor(rs, 4);
            rs += __shfl_xor(rs, 8);
            lrow[reg] = lrow[reg] * alpha[reg] + rs;
            #pragma unroll
            for (int fd = 0; fd < 4; ++fd) oacc[fd][reg] *= alpha[reg];
        }

        // ---- O += P V (P wave-private; V from transposed LDS) ----
        #pragma unroll
        for (int ks = 0; ks < 2; ++ks) {
            const v8bf pa = *reinterpret_cast<const v8bf*>(
                &Pl[wid][li * 64 + (((ks * 4 + g) ^ (li & 7)) << 3)]);
            #pragma unroll
            for (int fd = 0; fd < 4; ++fd) {
                const int dr = fd * 16 + li;
                const v8bf vb = *reinterpret_cast<const v8bf*>(
                    &Vt[cur][dr * 64 + (((ks * 4 + g) ^ (dr & 7)) << 3)]);
                oacc[fd] = MFMA16(pa, vb, oacc[fd]);
            }
        }

        // ---- write prefetched tiles to the other LDS buffers ----
        if (t < 31) {
            *reinterpret_cast<v8bf*>(&Kl[nxt][srow0 * 64 + ((sblk ^ (srow0 & 7)) << 3)]) = kreg[0];
            *reinterpret_cast<v8bf*>(&Kl[nxt][srow1 * 64 + ((sblk ^ (srow1 & 7)) << 3)]) = kreg[1];
            #pragma unroll
            for (int j = 0; j < 16; ++j) {
                const int d = vdb * 16 + j;
                Vt[nxt][d * 64 + (((vm >> 3) ^ (d & 7)) << 3) + (vm & 7)] =
                    (j < 8) ? vreg[0][j] : vreg[1][j - 8];
            }
            if (relNext) {
                *reinterpret_cast<v8bf*>(&El[nxt][srow0 * 64 + ((sblk ^ (srow0 & 7)) << 3)]) = ereg[0];
                *reinterpret_cast<v8bf*>(&El[nxt][srow1 * 64 + ((sblk ^ (srow1 & 7)) << 3)]) = ereg[1];
            }
        }
        __syncthreads();
    }

    // ---- normalize + store ao (bf16, [b*2048+l][h*64+d]) ----
    const int b = bh >> 4, h = bh & 15;
    #pragma unroll
    for (int reg = 0; reg < 4; ++reg) {
        const float inv = 1.0f / lrow[reg];
        const int row = l0 + wid * 16 + 4 * g + reg;
        #pragma unroll
        for (int fd = 0; fd < 4; ++fd) {
            const int col = h * 64 + fd * 16 + li;
            ao[(size_t)(b * 2048 + row) * 1024 + col] = (__bf16)(oacc[fd][reg] * inv);
        }
    }
}

extern "C" void kernel_launch(void* const* d_in, const int* in_sizes, int n_in,
                              void* d_out, int out_size, void* d_ws, size_t ws_size,
                              hipStream_t stream) {
    (void)in_sizes; (void)n_in; (void)out_size; (void)ws_size;
    const float* query = (const float*)d_in[0];
    const float* key   = (const float*)d_in[1];
    const float* value = (const float*)d_in[2];
    const float* Wq    = (const float*)d_in[3];
    const float* bq    = (const float*)d_in[4];
    const float* Wk    = (const float*)d_in[5];
    const float* bk    = (const float*)d_in[6];
    const float* Wv    = (const float*)d_in[7];
    const float* bv    = (const float*)d_in[8];
    const float* Wo    = (const float*)d_in[9];
    const float* bo    = (const float*)d_in[10];
    const float* rel   = (const float*)d_in[11];
    float* out = (float*)d_out;

    __bf16* q_bf = (__bf16*)d_ws;            // [32][2048][64]
    __bf16* k_bf = q_bf + 4194304;
    __bf16* v_bf = k_bf + 4194304;
    __bf16* act  = v_bf + 4194304;           // [4096][1024] cast buffer (reused)
    __bf16* aob  = act + 4194304;            // [4096][1024] attention output
    __bf16* Wt   = aob + 4194304;            // [1024][1024] transposed weight (reused)
    __bf16* E_bf = Wt + 1048576;             // [2112][64]

    const dim3 blk(256);
    const dim3 ggemm(16, 32);
    const dim3 gtw(16, 16);

    cast_rel<<<132, blk, 0, stream>>>(rel, E_bf);

    transpose_cast_w<<<gtw, blk, 0, stream>>>(Wq, Wt);
    cast_f32_bf16<<<4096, blk, 0, stream>>>(query, act, 1048576);
    gemm_bf16<<<ggemm, blk, 0, stream>>>(act, Wt, bq, nullptr, q_bf, 1);

    transpose_cast_w<<<gtw, blk, 0, stream>>>(Wk, Wt);
    cast_f32_bf16<<<4096, blk, 0, stream>>>(key, act, 1048576);
    gemm_bf16<<<ggemm, blk, 0, stream>>>(act, Wt, bk, nullptr, k_bf, 1);

    transpose_cast_w<<<gtw, blk, 0, stream>>>(Wv, Wt);
    cast_f32_bf16<<<4096, blk, 0, stream>>>(value, act, 1048576);
    gemm_bf16<<<ggemm, blk, 0, stream>>>(act, Wt, bv, nullptr, v_bf, 1);

    attn_mfma<<<dim3(32, 32), blk, 0, stream>>>(q_bf, k_bf, v_bf, E_bf, aob);

    transpose_cast_w<<<gtw, blk, 0, stream>>>(Wo, Wt);
    gemm_bf16<<<ggemm, blk, 0, stream>>>(aob, Wt, bo, out, nullptr, 0);
}

// Round 3
// 276.936 us; speedup vs baseline: 19.0794x; 1.1086x over previous
//
#include <hip/hip_runtime.h>
#include <hip/hip_bf16.h>

// B=2, L=2048, D=1024, H=16, DH=64, M=2048
// logits[l,m] = (q[l].k[m] + (m<=l ? q[l].E[2047+m-l] : 0)) / 8, E[j]=rel[j+1]
// softmax over all m (no causal mask), out = (attn@v reshaped) @ Wo + bo
// bf16 MFMA pipeline; rel via incremental banded GEMM + shifted gather.
// Round 3: no-max deferred-sum softmax (logits bounded ~|2|), V pre-transposed
// (b128 staging), cast fused into GEMM, setprio around MFMA clusters.

typedef __bf16 v8bf __attribute__((ext_vector_type(8)));
typedef __bf16 v4bf __attribute__((ext_vector_type(4)));
typedef float f32x4 __attribute__((ext_vector_type(4)));

#define MFMA16(A, B, C) __builtin_amdgcn_mfma_f32_16x16x32_bf16((A), (B), (C), 0, 0, 0)

// ---------------- rel[1:2049] -> E_bf [2112][64] bf16, zero-padded ----------------
__global__ __launch_bounds__(256)
void cast_rel(const float* __restrict__ rel, __bf16* __restrict__ E)
{
    const int i = blockIdx.x * 256 + threadIdx.x;   // unit = 4 elems; 2112*16 units
    if (i >= 2112 * 16) return;
    const int base = i * 4;
    const int row = base >> 6;
    v4bf o;
    if (row < 2048) {
        const float4 v = *reinterpret_cast<const float4*>(&rel[(size_t)(row + 1) * 64 + (base & 63)]);
        o[0] = (__bf16)v.x; o[1] = (__bf16)v.y; o[2] = (__bf16)v.z; o[3] = (__bf16)v.w;
    } else {
        o[0] = (__bf16)0.f; o[1] = (__bf16)0.f; o[2] = (__bf16)0.f; o[3] = (__bf16)0.f;
    }
    *reinterpret_cast<v4bf*>(&E[base]) = o;
}

// ---------------- W [1024][1024] fp32 -> Wt [n][k] bf16 (transpose+cast) ----------------
__global__ __launch_bounds__(256)
void transpose_cast_w(const float* __restrict__ W, __bf16* __restrict__ Wt)
{
    __shared__ float tile[64][65];
    const int r0 = blockIdx.y * 64, c0 = blockIdx.x * 64;
    const int tr = threadIdx.x >> 4;
    const int tc = (threadIdx.x & 15) * 4;
    #pragma unroll
    for (int p = 0; p < 4; ++p) {
        const int r = tr + p * 16;
        const float4 v = *reinterpret_cast<const float4*>(&W[(size_t)(r0 + r) * 1024 + c0 + tc]);
        tile[r][tc + 0] = v.x; tile[r][tc + 1] = v.y; tile[r][tc + 2] = v.z; tile[r][tc + 3] = v.w;
    }
    __syncthreads();
    #pragma unroll
    for (int p = 0; p < 4; ++p) {
        const int cr = tr + p * 16;          // output row = original column
        v4bf o;
        o[0] = (__bf16)tile[tc + 0][cr];
        o[1] = (__bf16)tile[tc + 1][cr];
        o[2] = (__bf16)tile[tc + 2][cr];
        o[3] = (__bf16)tile[tc + 3][cr];
        *reinterpret_cast<v4bf*>(&Wt[(size_t)(c0 + cr) * 1024 + r0 + tc]) = o;
    }
}

// ---------------- bf16 MFMA GEMM: C = A[4096x1024](fp32) @ Wt^T + bias ----------------
// Wt is [n][k] bf16 (pre-transposed); A cast to bf16 during staging.
// mode 0: fp32 flat out; mode 1: bf16 heads [bh][l][64]; mode 2: bf16 [bh][dh][2048]
__global__ __launch_bounds__(256)
void gemm_bf16(const float* __restrict__ A, const __bf16* __restrict__ Wt,
               const float* __restrict__ bias, float* __restrict__ Cf,
               __bf16* __restrict__ Cb, int mode)
{
    __shared__ __bf16 As[2][128 * 64];
    __shared__ __bf16 Ws[2][64 * 64];
    const int tid = threadIdx.x;
    const int wid = tid >> 6, lane = tid & 63, g = lane >> 4, li = lane & 15;
    const int r0 = blockIdx.y * 128, c0 = blockIdx.x * 64;
    const int wr = wid >> 1, wc = wid & 1;
    const int sr = tid >> 3, sb = tid & 7;

    f32x4 acc[4][2];
    #pragma unroll
    for (int a = 0; a < 4; ++a)
        #pragma unroll
        for (int b2 = 0; b2 < 2; ++b2) acc[a][b2] = f32x4{0.f, 0.f, 0.f, 0.f};

    v8bf areg[4], wreg[2];

    auto loadA = [&](int p, int kt) {
        const float* ar = &A[(size_t)(r0 + sr + 32 * p) * 1024 + kt + sb * 8];
        const float4 f0 = *reinterpret_cast<const float4*>(ar);
        const float4 f1 = *reinterpret_cast<const float4*>(ar + 4);
        v8bf a8;
        a8[0] = (__bf16)f0.x; a8[1] = (__bf16)f0.y; a8[2] = (__bf16)f0.z; a8[3] = (__bf16)f0.w;
        a8[4] = (__bf16)f1.x; a8[5] = (__bf16)f1.y; a8[6] = (__bf16)f1.z; a8[7] = (__bf16)f1.w;
        return a8;
    };

    // prologue stage kt=0
    #pragma unroll
    for (int p = 0; p < 4; ++p) areg[p] = loadA(p, 0);
    #pragma unroll
    for (int p = 0; p < 2; ++p)
        wreg[p] = *reinterpret_cast<const v8bf*>(&Wt[(size_t)(c0 + sr + 32 * p) * 1024 + sb * 8]);
    #pragma unroll
    for (int p = 0; p < 4; ++p) {
        const int row = sr + 32 * p;
        *reinterpret_cast<v8bf*>(&As[0][row * 64 + ((sb ^ (row & 7)) << 3)]) = areg[p];
    }
    #pragma unroll
    for (int p = 0; p < 2; ++p) {
        const int row = sr + 32 * p;
        *reinterpret_cast<v8bf*>(&Ws[0][row * 64 + ((sb ^ (row & 7)) << 3)]) = wreg[p];
    }
    __syncthreads();

    for (int ki = 0; ki < 16; ++ki) {
        const int cur = ki & 1;
        if (ki < 15) {
            const int kt = (ki + 1) * 64;
            #pragma unroll
            for (int p = 0; p < 4; ++p) areg[p] = loadA(p, kt);
            #pragma unroll
            for (int p = 0; p < 2; ++p)
                wreg[p] = *reinterpret_cast<const v8bf*>(&Wt[(size_t)(c0 + sr + 32 * p) * 1024 + kt + sb * 8]);
        }
        #pragma unroll
        for (int ks = 0; ks < 2; ++ks) {
            v8bf af[4], bfr[2];
            #pragma unroll
            for (int fm = 0; fm < 4; ++fm) {
                const int row = wr * 64 + fm * 16 + li;
                af[fm] = *reinterpret_cast<const v8bf*>(
                    &As[cur][row * 64 + (((ks * 4 + g) ^ (row & 7)) << 3)]);
            }
            #pragma unroll
            for (int fn = 0; fn < 2; ++fn) {
                const int row = wc * 32 + fn * 16 + li;
                bfr[fn] = *reinterpret_cast<const v8bf*>(
                    &Ws[cur][row * 64 + (((ks * 4 + g) ^ (row & 7)) << 3)]);
            }
            __builtin_amdgcn_s_setprio(1);
            #pragma unroll
            for (int fm = 0; fm < 4; ++fm)
                #pragma unroll
                for (int fn = 0; fn < 2; ++fn)
                    acc[fm][fn] = MFMA16(af[fm], bfr[fn], acc[fm][fn]);
            __builtin_amdgcn_s_setprio(0);
        }
        if (ki < 15) {
            const int nxt = cur ^ 1;
            #pragma unroll
            for (int p = 0; p < 4; ++p) {
                const int row = sr + 32 * p;
                *reinterpret_cast<v8bf*>(&As[nxt][row * 64 + ((sb ^ (row & 7)) << 3)]) = areg[p];
            }
            #pragma unroll
            for (int p = 0; p < 2; ++p) {
                const int row = sr + 32 * p;
                *reinterpret_cast<v8bf*>(&Ws[nxt][row * 64 + ((sb ^ (row & 7)) << 3)]) = wreg[p];
            }
        }
        __syncthreads();
    }

    // epilogue
    #pragma unroll
    for (int fn = 0; fn < 2; ++fn) {
        const int col = c0 + wc * 32 + fn * 16 + li;
        const float bb = bias[col];
        #pragma unroll
        for (int fm = 0; fm < 4; ++fm) {
            if (mode == 2) {
                const int row = r0 + wr * 64 + fm * 16 + 4 * g;     // 4 consecutive rows
                const int b = row >> 11, l = row & 2047;
                const int h = col >> 6, dh = col & 63;
                v4bf pk;
                #pragma unroll
                for (int reg = 0; reg < 4; ++reg)
                    pk[reg] = (__bf16)(acc[fm][fn][reg] + bb);
                *reinterpret_cast<v4bf*>(
                    &Cb[((size_t)((b * 16 + h) * 64 + dh)) * 2048 + l]) = pk;
            } else {
                #pragma unroll
                for (int reg = 0; reg < 4; ++reg) {
                    const int row = r0 + wr * 64 + fm * 16 + 4 * g + reg;
                    const float val = acc[fm][fn][reg] + bb;
                    if (mode == 0) {
                        Cf[(size_t)row * 1024 + col] = val;
                    } else {
                        const int b = row >> 11, l = row & 2047, h = col >> 6, dh = col & 63;
                        Cb[((size_t)(b * 16 + h) * 2048 + l) * 64 + dh] = (__bf16)val;
                    }
                }
            }
        }
    }
}

// ---------------- fused MFMA flash attention with banded-GEMM rel ----------------
// q,k: [32][2048][64] bf16; vt: [32][64][2048] bf16 (pre-transposed V);
// E: [2112][64] bf16; ao: [4096][1024] fp32.
// Block = 256 thr = 4 waves, 64 queries; 32 m-steps of 64.
// No-max softmax: p = exp2(c*s) with c = log2e/8; row-sum deferred to end.
__global__ __launch_bounds__(256)
void attn_mfma(const __bf16* __restrict__ q, const __bf16* __restrict__ k,
               const __bf16* __restrict__ vt, const __bf16* __restrict__ E,
               float* __restrict__ ao)
{
    __shared__ __bf16 Kl[2][64 * 64];     // [m][d], 16B-block XOR swizzle
    __shared__ __bf16 Vl[2][64 * 64];     // [d][m], swizzled (from pre-transposed vt)
    __shared__ __bf16 El[2][64 * 64];     // e-window rows, swizzled
    __shared__ __bf16 Tl[64 * 136];       // T gather buf: cols [0,68)=buf0, [68,136)=buf1
    __shared__ __bf16 Pl[4][16 * 64];     // per-wave P strip, swizzled

    const int tid = threadIdx.x;
    const int wid = tid >> 6, lane = tid & 63, g = lane >> 4, li = lane & 15;
    const int qt = blockIdx.x, bh = blockIdx.y;
    const int l0 = qt * 64;
    const size_t hbase = (size_t)bh * (2048 * 64);
    const __bf16* qp = q + hbase;
    const __bf16* kp = k + hbase;
    const __bf16* vtp = vt + hbase;       // [64][2048]
    const int w0i = 1984 - 64 * qt;       // first e-block base (>=0)

    const int srow0 = tid >> 3, sblk = tid & 7, srow1 = srow0 + 32;
    constexpr float kScale = 0.1803368801111244f;   // log2(e)/8

    // Q A-fragments, held in registers for whole kernel
    v8bf qf[2];
    {
        const __bf16* qrow = qp + (size_t)(l0 + wid * 16 + li) * 64 + g * 8;
        qf[0] = *reinterpret_cast<const v8bf*>(qrow);
        qf[1] = *reinterpret_cast<const v8bf*>(qrow + 32);
    }

    f32x4 oacc[4];
    #pragma unroll
    for (int i = 0; i < 4; ++i) oacc[i] = f32x4{0.f, 0.f, 0.f, 0.f};
    float lrow[4] = {0.f, 0.f, 0.f, 0.f};

    v8bf kreg[2], vreg[2], ereg[2];

    // ---- prologue staging: K[0], V[0], E lo -> El[1], E hi(t=0) -> El[0] ----
    kreg[0] = *reinterpret_cast<const v8bf*>(&kp[(size_t)srow0 * 64 + sblk * 8]);
    kreg[1] = *reinterpret_cast<const v8bf*>(&kp[(size_t)srow1 * 64 + sblk * 8]);
    vreg[0] = *reinterpret_cast<const v8bf*>(&vtp[(size_t)srow0 * 2048 + sblk * 8]);
    vreg[1] = *reinterpret_cast<const v8bf*>(&vtp[(size_t)srow1 * 2048 + sblk * 8]);
    ereg[0] = *reinterpret_cast<const v8bf*>(&E[(size_t)(w0i + srow0) * 64 + sblk * 8]);
    ereg[1] = *reinterpret_cast<const v8bf*>(&E[(size_t)(w0i + srow1) * 64 + sblk * 8]);
    v8bf ereg2[2];
    ereg2[0] = *reinterpret_cast<const v8bf*>(&E[(size_t)(w0i + 64 + srow0) * 64 + sblk * 8]);
    ereg2[1] = *reinterpret_cast<const v8bf*>(&E[(size_t)(w0i + 64 + srow1) * 64 + sblk * 8]);

    *reinterpret_cast<v8bf*>(&Kl[0][srow0 * 64 + ((sblk ^ (srow0 & 7)) << 3)]) = kreg[0];
    *reinterpret_cast<v8bf*>(&Kl[0][srow1 * 64 + ((sblk ^ (srow1 & 7)) << 3)]) = kreg[1];
    *reinterpret_cast<v8bf*>(&Vl[0][srow0 * 64 + ((sblk ^ (srow0 & 7)) << 3)]) = vreg[0];
    *reinterpret_cast<v8bf*>(&Vl[0][srow1 * 64 + ((sblk ^ (srow1 & 7)) << 3)]) = vreg[1];
    *reinterpret_cast<v8bf*>(&El[1][srow0 * 64 + ((sblk ^ (srow0 & 7)) << 3)]) = ereg[0];
    *reinterpret_cast<v8bf*>(&El[1][srow1 * 64 + ((sblk ^ (srow1 & 7)) << 3)]) = ereg[1];
    *reinterpret_cast<v8bf*>(&El[0][srow0 * 64 + ((sblk ^ (srow0 & 7)) << 3)]) = ereg2[0];
    *reinterpret_cast<v8bf*>(&El[0][srow1 * 64 + ((sblk ^ (srow1 & 7)) << 3)]) = ereg2[1];
    __syncthreads();

    // ---- prologue T-GEMM: lo block (El[1]) -> Tl cols [0,68) ----
    {
        f32x4 tacc[4];
        #pragma unroll
        for (int i = 0; i < 4; ++i) tacc[i] = f32x4{0.f, 0.f, 0.f, 0.f};
        #pragma unroll
        for (int ks = 0; ks < 2; ++ks)
            #pragma unroll
            for (int rn = 0; rn < 4; ++rn) {
                const int er = rn * 16 + li;
                const v8bf eb = *reinterpret_cast<const v8bf*>(
                    &El[1][er * 64 + (((ks * 4 + g) ^ (er & 7)) << 3)]);
                tacc[rn] = MFMA16(qf[ks], eb, tacc[rn]);
            }
        #pragma unroll
        for (int rn = 0; rn < 4; ++rn)
            #pragma unroll
            for (int reg = 0; reg < 4; ++reg)
                Tl[(wid * 16 + 4 * g + reg) * 136 + rn * 16 + li] = (__bf16)tacc[rn][reg];
    }
    __syncthreads();   // protect El[1] from t=0's prefetch overwrite

    for (int t = 0; t < 32; ++t) {
        const int cur = t & 1, nxt = cur ^ 1;
        const bool relNow = (t <= qt);
        const bool relNext = (t + 1 <= qt);

        // ---- prefetch next tiles into registers (written to LDS after compute) ----
        if (t < 31) {
            const int m1 = (t + 1) * 64;
            kreg[0] = *reinterpret_cast<const v8bf*>(&kp[(size_t)(m1 + srow0) * 64 + sblk * 8]);
            kreg[1] = *reinterpret_cast<const v8bf*>(&kp[(size_t)(m1 + srow1) * 64 + sblk * 8]);
            vreg[0] = *reinterpret_cast<const v8bf*>(&vtp[(size_t)srow0 * 2048 + m1 + sblk * 8]);
            vreg[1] = *reinterpret_cast<const v8bf*>(&vtp[(size_t)srow1 * 2048 + m1 + sblk * 8]);
            if (relNext) {
                const int wb = w0i + 64 * (t + 1) + 64;
                ereg[0] = *reinterpret_cast<const v8bf*>(&E[(size_t)(wb + srow0) * 64 + sblk * 8]);
                ereg[1] = *reinterpret_cast<const v8bf*>(&E[(size_t)(wb + srow1) * 64 + sblk * 8]);
            }
        }

        // ---- S = Q K^T ----
        f32x4 sacc[4];
        #pragma unroll
        for (int i = 0; i < 4; ++i) sacc[i] = f32x4{0.f, 0.f, 0.f, 0.f};
        #pragma unroll
        for (int ks = 0; ks < 2; ++ks) {
            v8bf kb[4];
            #pragma unroll
            for (int fn = 0; fn < 4; ++fn) {
                const int kr = fn * 16 + li;
                kb[fn] = *reinterpret_cast<const v8bf*>(
                    &Kl[cur][kr * 64 + (((ks * 4 + g) ^ (kr & 7)) << 3)]);
            }
            __builtin_amdgcn_s_setprio(1);
            #pragma unroll
            for (int fn = 0; fn < 4; ++fn)
                sacc[fn] = MFMA16(qf[ks], kb[fn], sacc[fn]);
            __builtin_amdgcn_s_setprio(0);
        }

        // ---- T-GEMM: new hi e-block (El[cur]) -> Tl cols [nxt*68, nxt*68+64) ----
        if (relNow) {
            f32x4 tacc[4];
            #pragma unroll
            for (int i = 0; i < 4; ++i) tacc[i] = f32x4{0.f, 0.f, 0.f, 0.f};
            #pragma unroll
            for (int ks = 0; ks < 2; ++ks) {
                v8bf eb[4];
                #pragma unroll
                for (int rn = 0; rn < 4; ++rn) {
                    const int er = rn * 16 + li;
                    eb[rn] = *reinterpret_cast<const v8bf*>(
                        &El[cur][er * 64 + (((ks * 4 + g) ^ (er & 7)) << 3)]);
                }
                __builtin_amdgcn_s_setprio(1);
                #pragma unroll
                for (int rn = 0; rn < 4; ++rn)
                    tacc[rn] = MFMA16(qf[ks], eb[rn], tacc[rn]);
                __builtin_amdgcn_s_setprio(0);
            }
            const int tb = nxt * 68;
            #pragma unroll
            for (int rn = 0; rn < 4; ++rn)
                #pragma unroll
                for (int reg = 0; reg < 4; ++reg)
                    Tl[(wid * 16 + 4 * g + reg) * 136 + tb + rn * 16 + li] = (__bf16)tacc[rn][reg];
        }

        // ---- rel gather (wave-private T rows; same-wave LDS ordering suffices) ----
        if (relNow) {
            const int lob = cur * 68, hib = nxt * 68;
            #pragma unroll
            for (int fn = 0; fn < 4; ++fn)
                #pragma unroll
                for (int reg = 0; reg < 4; ++reg) {
                    const int lr = wid * 16 + 4 * g + reg;     // tile-local l row
                    const int mc = fn * 16 + li;               // tile-local m col
                    const int colv = 63 + mc - lr;             // 0..126
                    const int addr = lr * 136 + (colv < 64 ? lob + colv : hib + colv - 64);
                    const float tv = (float)Tl[addr];
                    if ((t < qt) || (mc <= lr)) sacc[fn][reg] += tv;
                }
        }

        // ---- no-max softmax: p = exp2(c*s); deferred row-sum ----
        #pragma unroll
        for (int fn = 0; fn < 4; ++fn) sacc[fn] *= kScale;
        #pragma unroll
        for (int fn = 0; fn < 4; ++fn)
            #pragma unroll
            for (int reg = 0; reg < 4; ++reg) {
                const float p = exp2f(sacc[fn][reg]);
                lrow[reg] += p;
                const int pr = 4 * g + reg;
                const int mc = fn * 16 + li;
                Pl[wid][pr * 64 + (((mc >> 3) ^ (pr & 7)) << 3) + (mc & 7)] = (__bf16)p;
            }

        // ---- O += P V (P wave-private; V from [d][m] LDS) ----
        #pragma unroll
        for (int ks = 0; ks < 2; ++ks) {
            const v8bf pa = *reinterpret_cast<const v8bf*>(
                &Pl[wid][li * 64 + (((ks * 4 + g) ^ (li & 7)) << 3)]);
            v8bf vb[4];
            #pragma unroll
            for (int fd = 0; fd < 4; ++fd) {
                const int dr = fd * 16 + li;
                vb[fd] = *reinterpret_cast<const v8bf*>(
                    &Vl[cur][dr * 64 + (((ks * 4 + g) ^ (dr & 7)) << 3)]);
            }
            __builtin_amdgcn_s_setprio(1);
            #pragma unroll
            for (int fd = 0; fd < 4; ++fd)
                oacc[fd] = MFMA16(pa, vb[fd], oacc[fd]);
            __builtin_amdgcn_s_setprio(0);
        }

        // ---- write prefetched tiles to the other LDS buffers ----
        if (t < 31) {
            *reinterpret_cast<v8bf*>(&Kl[nxt][srow0 * 64 + ((sblk ^ (srow0 & 7)) << 3)]) = kreg[0];
            *reinterpret_cast<v8bf*>(&Kl[nxt][srow1 * 64 + ((sblk ^ (srow1 & 7)) << 3)]) = kreg[1];
            *reinterpret_cast<v8bf*>(&Vl[nxt][srow0 * 64 + ((sblk ^ (srow0 & 7)) << 3)]) = vreg[0];
            *reinterpret_cast<v8bf*>(&Vl[nxt][srow1 * 64 + ((sblk ^ (srow1 & 7)) << 3)]) = vreg[1];
            if (relNext) {
                *reinterpret_cast<v8bf*>(&El[nxt][srow0 * 64 + ((sblk ^ (srow0 & 7)) << 3)]) = ereg[0];
                *reinterpret_cast<v8bf*>(&El[nxt][srow1 * 64 + ((sblk ^ (srow1 & 7)) << 3)]) = ereg[1];
            }
        }
        __syncthreads();
    }

    // ---- end: reduce row-sums across the 16-lane li-group, normalize, store ----
    const int b = bh >> 4, h = bh & 15;
    #pragma unroll
    for (int reg = 0; reg < 4; ++reg) {
        float rs = lrow[reg];
        rs += __shfl_xor(rs, 1);
        rs += __shfl_xor(rs, 2);
        rs += __shfl_xor(rs, 4);
        rs += __shfl_xor(rs, 8);
        const float inv = 1.0f / rs;
        const int row = l0 + wid * 16 + 4 * g + reg;
        #pragma unroll
        for (int fd = 0; fd < 4; ++fd) {
            const int col = h * 64 + fd * 16 + li;
            ao[(size_t)(b * 2048 + row) * 1024 + col] = oacc[fd][reg] * inv;
        }
    }
}

extern "C" void kernel_launch(void* const* d_in, const int* in_sizes, int n_in,
                              void* d_out, int out_size, void* d_ws, size_t ws_size,
                              hipStream_t stream) {
    (void)in_sizes; (void)n_in; (void)out_size; (void)ws_size;
    const float* query = (const float*)d_in[0];
    const float* key   = (const float*)d_in[1];
    const float* value = (const float*)d_in[2];
    const float* Wq    = (const float*)d_in[3];
    const float* bq    = (const float*)d_in[4];
    const float* Wk    = (const float*)d_in[5];
    const float* bk    = (const float*)d_in[6];
    const float* Wv    = (const float*)d_in[7];
    const float* bv    = (const float*)d_in[8];
    const float* Wo    = (const float*)d_in[9];
    const float* bo    = (const float*)d_in[10];
    const float* rel   = (const float*)d_in[11];
    float* out = (float*)d_out;

    __bf16* q_bf  = (__bf16*)d_ws;           // [32][2048][64]   8 MiB
    __bf16* k_bf  = q_bf + 4194304;          //                  8 MiB
    __bf16* vt_bf = k_bf + 4194304;          // [32][64][2048]   8 MiB
    __bf16* Wt    = vt_bf + 4194304;         // [1024][1024]     2 MiB
    __bf16* E_bf  = Wt + 1048576;            // [2112][64]       0.26 MiB
    float*  ao    = (float*)(E_bf + 135168); // [4096][1024]     16 MiB

    const dim3 blk(256);
    const dim3 ggemm(16, 32);
    const dim3 gtw(16, 16);

    cast_rel<<<132, blk, 0, stream>>>(rel, E_bf);

    transpose_cast_w<<<gtw, blk, 0, stream>>>(Wq, Wt);
    gemm_bf16<<<ggemm, blk, 0, stream>>>(query, Wt, bq, nullptr, q_bf, 1);

    transpose_cast_w<<<gtw, blk, 0, stream>>>(Wk, Wt);
    gemm_bf16<<<ggemm, blk, 0, stream>>>(key, Wt, bk, nullptr, k_bf, 1);

    transpose_cast_w<<<gtw, blk, 0, stream>>>(Wv, Wt);
    gemm_bf16<<<ggemm, blk, 0, stream>>>(value, Wt, bv, nullptr, vt_bf, 2);

    attn_mfma<<<dim3(32, 32), blk, 0, stream>>>(q_bf, k_bf, vt_bf, E_bf, ao);

    transpose_cast_w<<<gtw, blk, 0, stream>>>(Wo, Wt);
    gemm_bf16<<<ggemm, blk, 0, stream>>>(ao, Wt, bo, out, nullptr, 0);
}

// Round 4
// 203.466 us; speedup vs baseline: 25.9688x; 1.3611x over previous
//
#include <hip/hip_runtime.h>
#include <hip/hip_bf16.h>

// B=2, L=2048, D=1024, H=16, DH=64, M=2048
// logits[l,m] = (q[l].k[m] + (m<=l ? q[l].E[2047+m-l] : 0)) / 8, E[j]=rel[j+1]
// softmax over all m (no causal mask), out = (attn@v reshaped) @ Wo + bo
// Round 4: 32x32x16 MFMA with swapped operands (l lane-local), QBLK=128/4 waves,
// single-buffered K/V LDS, E via direct-global A-frags, vectorized T/P writes,
// XCD-aware block remap, bf16 attention output, consolidated launches.

typedef __bf16 v8bf __attribute__((ext_vector_type(8)));
typedef __bf16 v4bf __attribute__((ext_vector_type(4)));
typedef float f32x4 __attribute__((ext_vector_type(4)));
typedef float f32x16 __attribute__((ext_vector_type(16)));

#define MFMA16(A,B,C) __builtin_amdgcn_mfma_f32_16x16x32_bf16((A),(B),(C),0,0,0)
#define MFMA32(A,B,C) __builtin_amdgcn_mfma_f32_32x32x16_bf16((A),(B),(C),0,0,0)

// ---------------- rel -> E_pad [2304][64] bf16: rows 128..2175 = rel[1:2049], else 0
__global__ __launch_bounds__(256)
void cast_rel(const float* __restrict__ rel, __bf16* __restrict__ E)
{
    const int i = blockIdx.x * 256 + threadIdx.x;   // 4-elem units, 2304*16 total
    if (i >= 2304 * 16) return;
    const int base = i * 4;
    const int row = base >> 6;
    const int prow = row - 128;
    v4bf o;
    if (prow >= 0 && prow < 2048) {
        const float4 v = *reinterpret_cast<const float4*>(&rel[(size_t)(prow + 1) * 64 + (base & 63)]);
        o[0] = (__bf16)v.x; o[1] = (__bf16)v.y; o[2] = (__bf16)v.z; o[3] = (__bf16)v.w;
    } else {
        o[0] = (__bf16)0.f; o[1] = (__bf16)0.f; o[2] = (__bf16)0.f; o[3] = (__bf16)0.f;
    }
    *reinterpret_cast<v4bf*>(&E[base]) = o;
}

// ---------------- 4x W [1024][1024] fp32 -> Wt [n][k] bf16 (transpose+cast) ----------------
__global__ __launch_bounds__(256)
void transpose_cast_w4(const float* __restrict__ W0, const float* __restrict__ W1,
                       const float* __restrict__ W2, const float* __restrict__ W3,
                       __bf16* __restrict__ Wt4)
{
    __shared__ float tile[64][65];
    const int z = blockIdx.z;
    const float* W = (z == 0) ? W0 : (z == 1) ? W1 : (z == 2) ? W2 : W3;
    __bf16* Wt = Wt4 + (size_t)z * 1048576;
    const int r0 = blockIdx.y * 64, c0 = blockIdx.x * 64;
    const int tr = threadIdx.x >> 4;
    const int tc = (threadIdx.x & 15) * 4;
    #pragma unroll
    for (int p = 0; p < 4; ++p) {
        const int r = tr + p * 16;
        const float4 v = *reinterpret_cast<const float4*>(&W[(size_t)(r0 + r) * 1024 + c0 + tc]);
        tile[r][tc + 0] = v.x; tile[r][tc + 1] = v.y; tile[r][tc + 2] = v.z; tile[r][tc + 3] = v.w;
    }
    __syncthreads();
    #pragma unroll
    for (int p = 0; p < 4; ++p) {
        const int cr = tr + p * 16;
        v4bf o;
        o[0] = (__bf16)tile[tc + 0][cr];
        o[1] = (__bf16)tile[tc + 1][cr];
        o[2] = (__bf16)tile[tc + 2][cr];
        o[3] = (__bf16)tile[tc + 3][cr];
        *reinterpret_cast<v4bf*>(&Wt[(size_t)(c0 + cr) * 1024 + r0 + tc]) = o;
    }
}

// ---------------- bf16 MFMA GEMM body: C = A[4096x1024] @ Wt^T + bias ----------------
// mode 0: fp32 flat out; mode 1: bf16 heads [bh][l][64]; mode 2: bf16 [bh][dh][2048]
template <bool ABF16>
__device__ __forceinline__
void gemm_body(const float* __restrict__ Af, const __bf16* __restrict__ Ab,
               const __bf16* __restrict__ Wt, const float* __restrict__ bias,
               float* __restrict__ Cf, __bf16* __restrict__ Cb, int mode,
               int bx, int by)
{
    __shared__ __bf16 As[2][128 * 64];
    __shared__ __bf16 Ws[2][64 * 64];
    const int tid = threadIdx.x;
    const int wid = tid >> 6, lane = tid & 63, g = lane >> 4, li = lane & 15;
    const int r0 = by * 128, c0 = bx * 64;
    const int wr = wid >> 1, wc = wid & 1;
    const int sr = tid >> 3, sb = tid & 7;

    f32x4 acc[4][2];
    #pragma unroll
    for (int a = 0; a < 4; ++a)
        #pragma unroll
        for (int b2 = 0; b2 < 2; ++b2) acc[a][b2] = f32x4{0.f, 0.f, 0.f, 0.f};

    v8bf areg[4], wreg[2];

    auto loadA = [&](int p, int kt) -> v8bf {
        if constexpr (ABF16) {
            return *reinterpret_cast<const v8bf*>(&Ab[(size_t)(r0 + sr + 32 * p) * 1024 + kt + sb * 8]);
        } else {
            const float* ar = &Af[(size_t)(r0 + sr + 32 * p) * 1024 + kt + sb * 8];
            const float4 f0 = *reinterpret_cast<const float4*>(ar);
            const float4 f1 = *reinterpret_cast<const float4*>(ar + 4);
            v8bf a8;
            a8[0] = (__bf16)f0.x; a8[1] = (__bf16)f0.y; a8[2] = (__bf16)f0.z; a8[3] = (__bf16)f0.w;
            a8[4] = (__bf16)f1.x; a8[5] = (__bf16)f1.y; a8[6] = (__bf16)f1.z; a8[7] = (__bf16)f1.w;
            return a8;
        }
    };

    #pragma unroll
    for (int p = 0; p < 4; ++p) areg[p] = loadA(p, 0);
    #pragma unroll
    for (int p = 0; p < 2; ++p)
        wreg[p] = *reinterpret_cast<const v8bf*>(&Wt[(size_t)(c0 + sr + 32 * p) * 1024 + sb * 8]);
    #pragma unroll
    for (int p = 0; p < 4; ++p) {
        const int row = sr + 32 * p;
        *reinterpret_cast<v8bf*>(&As[0][row * 64 + ((sb ^ (row & 7)) << 3)]) = areg[p];
    }
    #pragma unroll
    for (int p = 0; p < 2; ++p) {
        const int row = sr + 32 * p;
        *reinterpret_cast<v8bf*>(&Ws[0][row * 64 + ((sb ^ (row & 7)) << 3)]) = wreg[p];
    }
    __syncthreads();

    for (int ki = 0; ki < 16; ++ki) {
        const int cur = ki & 1;
        if (ki < 15) {
            const int kt = (ki + 1) * 64;
            #pragma unroll
            for (int p = 0; p < 4; ++p) areg[p] = loadA(p, kt);
            #pragma unroll
            for (int p = 0; p < 2; ++p)
                wreg[p] = *reinterpret_cast<const v8bf*>(&Wt[(size_t)(c0 + sr + 32 * p) * 1024 + kt + sb * 8]);
        }
        #pragma unroll
        for (int ks = 0; ks < 2; ++ks) {
            v8bf af[4], bfr[2];
            #pragma unroll
            for (int fm = 0; fm < 4; ++fm) {
                const int row = wr * 64 + fm * 16 + li;
                af[fm] = *reinterpret_cast<const v8bf*>(
                    &As[cur][row * 64 + (((ks * 4 + g) ^ (row & 7)) << 3)]);
            }
            #pragma unroll
            for (int fn = 0; fn < 2; ++fn) {
                const int row = wc * 32 + fn * 16 + li;
                bfr[fn] = *reinterpret_cast<const v8bf*>(
                    &Ws[cur][row * 64 + (((ks * 4 + g) ^ (row & 7)) << 3)]);
            }
            __builtin_amdgcn_s_setprio(1);
            #pragma unroll
            for (int fm = 0; fm < 4; ++fm)
                #pragma unroll
                for (int fn = 0; fn < 2; ++fn)
                    acc[fm][fn] = MFMA16(af[fm], bfr[fn], acc[fm][fn]);
            __builtin_amdgcn_s_setprio(0);
        }
        if (ki < 15) {
            const int nxt = cur ^ 1;
            #pragma unroll
            for (int p = 0; p < 4; ++p) {
                const int row = sr + 32 * p;
                *reinterpret_cast<v8bf*>(&As[nxt][row * 64 + ((sb ^ (row & 7)) << 3)]) = areg[p];
            }
            #pragma unroll
            for (int p = 0; p < 2; ++p) {
                const int row = sr + 32 * p;
                *reinterpret_cast<v8bf*>(&Ws[nxt][row * 64 + ((sb ^ (row & 7)) << 3)]) = wreg[p];
            }
        }
        __syncthreads();
    }

    #pragma unroll
    for (int fn = 0; fn < 2; ++fn) {
        const int col = c0 + wc * 32 + fn * 16 + li;
        const float bb = bias[col];
        #pragma unroll
        for (int fm = 0; fm < 4; ++fm) {
            if (mode == 2) {
                const int row = r0 + wr * 64 + fm * 16 + 4 * g;
                const int b = row >> 11, l = row & 2047;
                const int h = col >> 6, dh = col & 63;
                v4bf pk;
                #pragma unroll
                for (int reg = 0; reg < 4; ++reg)
                    pk[reg] = (__bf16)(acc[fm][fn][reg] + bb);
                *reinterpret_cast<v4bf*>(&Cb[((size_t)((b * 16 + h) * 64 + dh)) * 2048 + l]) = pk;
            } else {
                #pragma unroll
                for (int reg = 0; reg < 4; ++reg) {
                    const int row = r0 + wr * 64 + fm * 16 + 4 * g + reg;
                    const float val = acc[fm][fn][reg] + bb;
                    if (mode == 0) {
                        Cf[(size_t)row * 1024 + col] = val;
                    } else {
                        const int b = row >> 11, l = row & 2047, h = col >> 6, dh = col & 63;
                        Cb[((size_t)(b * 16 + h) * 2048 + l) * 64 + dh] = (__bf16)val;
                    }
                }
            }
        }
    }
}

__global__ __launch_bounds__(256)
void gemm_proj3(const float* __restrict__ Aq, const float* __restrict__ Ak,
                const float* __restrict__ Av, const __bf16* __restrict__ Wt4,
                const float* __restrict__ bq, const float* __restrict__ bk,
                const float* __restrict__ bv, __bf16* __restrict__ qo,
                __bf16* __restrict__ ko, __bf16* __restrict__ vto)
{
    const int z = blockIdx.z;
    const float* A = (z == 0) ? Aq : (z == 1) ? Ak : Av;
    const __bf16* Wt = Wt4 + (size_t)z * 1048576;
    const float* bias = (z == 0) ? bq : (z == 1) ? bk : bv;
    __bf16* Cb = (z == 0) ? qo : (z == 1) ? ko : vto;
    gemm_body<false>(A, nullptr, Wt, bias, nullptr, Cb, (z == 2) ? 2 : 1,
                     blockIdx.x, blockIdx.y);
}

__global__ __launch_bounds__(256)
void gemm_out(const __bf16* __restrict__ A, const __bf16* __restrict__ Wt,
              const float* __restrict__ bias, float* __restrict__ C)
{
    gemm_body<true>(nullptr, A, Wt, bias, C, nullptr, 0, blockIdx.x, blockIdx.y);
}

// ---------------- fused attention: 32x32 MFMA, swapped operands ----------------
// q,k: [32][2048][64] bf16; vt: [32][64][2048] bf16; Ep: padded E (row -128..2175 valid)
// ao: [4096][1024] bf16. Block = 256 thr = 4 waves x 32 q-rows; 32 m-steps of 64.
__global__ __launch_bounds__(256, 2)
void attn_mfma(const __bf16* __restrict__ q, const __bf16* __restrict__ k,
               const __bf16* __restrict__ vt, const __bf16* __restrict__ Ep,
               __bf16* __restrict__ ao)
{
    __shared__ __bf16 Kl[64 * 64];        // [m][d], 16B-block XOR swizzle (8K)
    __shared__ __bf16 Vl[64 * 64];        // [d][m], swizzled (8K)
    __shared__ __bf16 Tl[4][32 * 132];    // per-wave T window [32 rows][128+4] (33K)
    __shared__ __bf16 Pl[4][32 * 72];     // per-wave P [32 rows][64+8] (18K)

    const int tid = threadIdx.x;
    const int wid = tid >> 6;
    const int lane = tid & 63;
    const int l31 = lane & 31;
    const int g2 = lane >> 5;

    // XCD-aware remap: all 16 q-tiles of a bh land on one XCD (K/V L2 locality)
    const int flat = blockIdx.y * 16 + blockIdx.x;
    const int jj_ = flat >> 3;
    const int bh = (flat & 7) * 4 + (jj_ >> 4);
    const int qt = jj_ & 15;

    const int l0 = qt * 128;
    const int lw0 = l0 + wid * 32;            // wave's first q-row
    const size_t hbase = (size_t)bh * (2048 * 64);
    const __bf16* qp = q + hbase;
    const __bf16* kp = k + hbase;
    const __bf16* vtp = vt + hbase;           // [64][2048]
    const int wb0 = 1984 - l0 - 32 * wid;     // per-wave e-window base at t=0

    __bf16* Tw = &Tl[wid][0];
    __bf16* Pw = &Pl[wid][0];

    constexpr float kScale = 0.1803368801111244f;   // log2(e)/8

    // Q B-fragments (col = l lane-local), one per 16-wide k-step
    v8bf qf[4];
    {
        const __bf16* qrow = qp + (size_t)(lw0 + l31) * 64 + g2 * 8;
        qf[0] = *reinterpret_cast<const v8bf*>(qrow);
        qf[1] = *reinterpret_cast<const v8bf*>(qrow + 16);
        qf[2] = *reinterpret_cast<const v8bf*>(qrow + 32);
        qf[3] = *reinterpret_cast<const v8bf*>(qrow + 48);
    }

    const int sr = tid >> 3, sb = tid & 7;

    auto eload = [&](int baseRow, v8bf eb[8]) {
        #pragma unroll
        for (int jc = 0; jc < 2; ++jc)
            #pragma unroll
            for (int ks = 0; ks < 4; ++ks)
                eb[jc * 4 + ks] = *reinterpret_cast<const v8bf*>(
                    Ep + (size_t)(baseRow + jc * 32 + l31) * 64 + ks * 16 + g2 * 8);
    };

    // T-GEMM: T[l][colBase + j_local] = q[l] . E[rows], j_local via D-layout
    auto tgemm = [&](const v8bf eb[8], int colBase) {
        #pragma unroll
        for (int jc = 0; jc < 2; ++jc) {
            f32x16 tacc;
            #pragma unroll
            for (int r = 0; r < 16; ++r) tacc[r] = 0.f;
            __builtin_amdgcn_s_setprio(1);
            #pragma unroll
            for (int ks = 0; ks < 4; ++ks)
                tacc = MFMA32(eb[jc * 4 + ks], qf[ks], tacc);
            __builtin_amdgcn_s_setprio(0);
            #pragma unroll
            for (int r2 = 0; r2 < 4; ++r2) {
                v4bf w;
                w[0] = (__bf16)tacc[4 * r2 + 0]; w[1] = (__bf16)tacc[4 * r2 + 1];
                w[2] = (__bf16)tacc[4 * r2 + 2]; w[3] = (__bf16)tacc[4 * r2 + 3];
                const int col = colBase + jc * 32 + 8 * r2 + 4 * g2;
                *reinterpret_cast<v4bf*>(Tw + l31 * 132 + col) = w;
            }
        }
    };

    // ---- prologue: stage K/V tile 0; T window [wb0, wb0+128) ----
    {
        const v8bf k0a = *reinterpret_cast<const v8bf*>(kp + (size_t)sr * 64 + sb * 8);
        const v8bf k0b = *reinterpret_cast<const v8bf*>(kp + (size_t)(sr + 32) * 64 + sb * 8);
        const v8bf v0a = *reinterpret_cast<const v8bf*>(vtp + (size_t)sr * 2048 + sb * 8);
        const v8bf v0b = *reinterpret_cast<const v8bf*>(vtp + (size_t)(sr + 32) * 2048 + sb * 8);
        v8bf ebA[8], ebB[8];
        eload(wb0, ebA);
        eload(wb0 + 64, ebB);
        *reinterpret_cast<v8bf*>(&Kl[sr * 64 + ((sb ^ (sr & 7)) << 3)]) = k0a;
        *reinterpret_cast<v8bf*>(&Kl[(sr + 32) * 64 + ((sb ^ (sr & 7)) << 3)]) = k0b;
        *reinterpret_cast<v8bf*>(&Vl[sr * 64 + ((sb ^ (sr & 7)) << 3)]) = v0a;
        *reinterpret_cast<v8bf*>(&Vl[(sr + 32) * 64 + ((sb ^ (sr & 7)) << 3)]) = v0b;
        __syncthreads();
        tgemm(ebA, 0);
        tgemm(ebB, 64);
    }

    f32x16 oacc[2];
    #pragma unroll
    for (int dc = 0; dc < 2; ++dc)
        #pragma unroll
        for (int r = 0; r < 16; ++r) oacc[dc][r] = 0.f;
    float lrow = 0.f;

    for (int t = 0; t < 32; ++t) {
        const int m0 = t * 64;
        const bool lastT = (t == 31);
        const bool needRel = (m0 <= lw0 + 31);
        const bool fullAdd = (m0 + 63 <= lw0);
        const bool needTnext = (m0 + 64 <= lw0 + 31);
        const int lob = 64 * (t & 1);

        // E loads for next window's hi block
        v8bf ebN[8];
        if (needTnext) eload(wb0 + 64 * t + 128, ebN);

        // K/V prefetch for t+1
        v8bf kra, krb, vra, vrb;
        if (!lastT) {
            const int m1 = m0 + 64;
            kra = *reinterpret_cast<const v8bf*>(kp + (size_t)(m1 + sr) * 64 + sb * 8);
            krb = *reinterpret_cast<const v8bf*>(kp + (size_t)(m1 + sr + 32) * 64 + sb * 8);
            vra = *reinterpret_cast<const v8bf*>(vtp + (size_t)sr * 2048 + m1 + sb * 8);
            vrb = *reinterpret_cast<const v8bf*>(vtp + (size_t)(sr + 32) * 2048 + m1 + sb * 8);
        }

        // ---- QK^T (swapped: D[col=l][row=m]) + rel gather + exp + pack, per 32-m chunk
        #pragma unroll
        for (int mc = 0; mc < 2; ++mc) {
            f32x16 sacc;
            #pragma unroll
            for (int r = 0; r < 16; ++r) sacc[r] = 0.f;
            __builtin_amdgcn_s_setprio(1);
            #pragma unroll
            for (int ks = 0; ks < 4; ++ks) {
                const int row = mc * 32 + l31;
                const v8bf kb = *reinterpret_cast<const v8bf*>(
                    &Kl[row * 64 + (((2 * ks + g2) ^ (l31 & 7)) << 3)]);
                sacc = MFMA32(kb, qf[ks], sacc);
            }
            __builtin_amdgcn_s_setprio(0);

            if (needRel) {
                const int cb = 63 - l31 + lob;
                if (fullAdd) {
                    #pragma unroll
                    for (int r2 = 0; r2 < 4; ++r2)
                        #pragma unroll
                        for (int i2 = 0; i2 < 4; ++i2) {
                            const int mtl = mc * 32 + 8 * r2 + 4 * g2 + i2;
                            const int c = (cb + mtl) & 127;
                            sacc[4 * r2 + i2] += (float)Tw[l31 * 132 + c];
                        }
                } else {
                    const int R = lw0 + l31 - m0;      // add iff m_tl <= R
                    #pragma unroll
                    for (int r2 = 0; r2 < 4; ++r2)
                        #pragma unroll
                        for (int i2 = 0; i2 < 4; ++i2) {
                            const int mtl = mc * 32 + 8 * r2 + 4 * g2 + i2;
                            const int c = (cb + mtl) & 127;
                            const float tv = (float)Tw[l31 * 132 + c];
                            sacc[4 * r2 + i2] += (mtl <= R) ? tv : 0.f;
                        }
                }
            }

            // exp2 + row-sum + pack P (bf16) into per-wave LDS
            #pragma unroll
            for (int jj = 0; jj < 4; ++jj) {
                const float p0 = exp2f(sacc[4 * jj + 0] * kScale);
                const float p1 = exp2f(sacc[4 * jj + 1] * kScale);
                const float p2 = exp2f(sacc[4 * jj + 2] * kScale);
                const float p3 = exp2f(sacc[4 * jj + 3] * kScale);
                lrow += (p0 + p1) + (p2 + p3);
                v4bf w;
                w[0] = (__bf16)p0; w[1] = (__bf16)p1; w[2] = (__bf16)p2; w[3] = (__bf16)p3;
                *reinterpret_cast<v4bf*>(Pw + l31 * 72 + mc * 32 + 8 * jj + 4 * g2) = w;
            }
        }

        // ---- new-hi T block for t+1 (after gather read the retiring lo cols) ----
        if (needTnext) tgemm(ebN, lob);

        // ---- O += P V  (A = V^T rows d, B = P cols l) ----
        #pragma unroll
        for (int ks = 0; ks < 4; ++ks) {
            const v8bf pa = *reinterpret_cast<const v8bf*>(Pw + l31 * 72 + ks * 16 + g2 * 8);
            __builtin_amdgcn_s_setprio(1);
            #pragma unroll
            for (int dc = 0; dc < 2; ++dc) {
                const int row = dc * 32 + l31;
                const v8bf vb = *reinterpret_cast<const v8bf*>(
                    &Vl[row * 64 + (((2 * ks + g2) ^ (l31 & 7)) << 3)]);
                oacc[dc] = MFMA32(vb, pa, oacc[dc]);
            }
            __builtin_amdgcn_s_setprio(0);
        }

        // ---- single-buffer K/V swap ----
        __syncthreads();
        if (!lastT) {
            *reinterpret_cast<v8bf*>(&Kl[sr * 64 + ((sb ^ (sr & 7)) << 3)]) = kra;
            *reinterpret_cast<v8bf*>(&Kl[(sr + 32) * 64 + ((sb ^ (sr & 7)) << 3)]) = krb;
            *reinterpret_cast<v8bf*>(&Vl[sr * 64 + ((sb ^ (sr & 7)) << 3)]) = vra;
            *reinterpret_cast<v8bf*>(&Vl[(sr + 32) * 64 + ((sb ^ (sr & 7)) << 3)]) = vrb;
        }
        __syncthreads();
    }

    // ---- epilogue: normalize, stage O in LDS (alias Tl), coalesced bf16 store ----
    lrow += __shfl_xor(lrow, 32);
    const float inv = 1.0f / lrow;

    __syncthreads();
    __bf16* Ol = &Tl[0][0];                   // [128][72] bf16 (18.4K <= 33K)
    #pragma unroll
    for (int dc = 0; dc < 2; ++dc)
        #pragma unroll
        for (int r2 = 0; r2 < 4; ++r2) {
            v4bf w;
            w[0] = (__bf16)(oacc[dc][4 * r2 + 0] * inv);
            w[1] = (__bf16)(oacc[dc][4 * r2 + 1] * inv);
            w[2] = (__bf16)(oacc[dc][4 * r2 + 2] * inv);
            w[3] = (__bf16)(oacc[dc][4 * r2 + 3] * inv);
            const int d0 = dc * 32 + 8 * r2 + 4 * g2;
            *reinterpret_cast<v4bf*>(Ol + (wid * 32 + l31) * 72 + d0) = w;
        }
    __syncthreads();

    const int b = bh >> 4, h = bh & 15;
    #pragma unroll
    for (int p = 0; p < 4; ++p) {
        const int row = p * 32 + (tid >> 3);
        const v8bf w = *reinterpret_cast<const v8bf*>(Ol + row * 72 + (tid & 7) * 8);
        *reinterpret_cast<v8bf*>(ao + (size_t)(b * 2048 + l0 + row) * 1024 + h * 64 + (tid & 7) * 8) = w;
    }
}

extern "C" void kernel_launch(void* const* d_in, const int* in_sizes, int n_in,
                              void* d_out, int out_size, void* d_ws, size_t ws_size,
                              hipStream_t stream) {
    (void)in_sizes; (void)n_in; (void)out_size; (void)ws_size;
    const float* query = (const float*)d_in[0];
    const float* key   = (const float*)d_in[1];
    const float* value = (const float*)d_in[2];
    const float* Wq    = (const float*)d_in[3];
    const float* bq    = (const float*)d_in[4];
    const float* Wk    = (const float*)d_in[5];
    const float* bk    = (const float*)d_in[6];
    const float* Wv    = (const float*)d_in[7];
    const float* bv    = (const float*)d_in[8];
    const float* Wo    = (const float*)d_in[9];
    const float* bo    = (const float*)d_in[10];
    const float* rel   = (const float*)d_in[11];
    float* out = (float*)d_out;

    __bf16* q_bf  = (__bf16*)d_ws;            // [32][2048][64]   8 MiB
    __bf16* k_bf  = q_bf + 4194304;           //                  8 MiB
    __bf16* vt_bf = k_bf + 4194304;           // [32][64][2048]   8 MiB
    __bf16* Wt4   = vt_bf + 4194304;          // 4x [1024][1024]  8 MiB
    __bf16* E_pad = Wt4 + 4194304;            // [2304][64]       0.28 MiB
    __bf16* aob   = E_pad + 147456;           // [4096][1024]     8 MiB

    const dim3 blk(256);

    cast_rel<<<144, blk, 0, stream>>>(rel, E_pad);
    transpose_cast_w4<<<dim3(16, 16, 4), blk, 0, stream>>>(Wq, Wk, Wv, Wo, Wt4);
    gemm_proj3<<<dim3(16, 32, 3), blk, 0, stream>>>(query, key, value, Wt4,
                                                    bq, bk, bv, q_bf, k_bf, vt_bf);
    attn_mfma<<<dim3(16, 32), blk, 0, stream>>>(q_bf, k_bf, vt_bf, E_pad + 128 * 64, aob);
    gemm_out<<<dim3(16, 32), blk, 0, stream>>>(aob, Wt4 + 3 * 1048576, bo, out);
}